// Round 1
// baseline (33467.743 us; speedup 1.0000x reference)
//
#include <hip/hip_runtime.h>
#include <stdint.h>

typedef __bf16 bf16x8 __attribute__((ext_vector_type(8)));
typedef short  s16x8  __attribute__((ext_vector_type(8)));
typedef float  f32x4  __attribute__((ext_vector_type(4)));

#define MFMA16(a, b, c) __builtin_amdgcn_mfma_f32_16x16x32_bf16((a), (b), (c), 0, 0, 0)

// ---------------- workspace layout (bytes) ----------------
#define OFF_X      0ull          // (T,64,512) bf16: xp, overwritten in-place by hs
#define OFF_QXBF   67108864ull   // (B,T,128) bf16 copy of q_x for emission
#define OFF_WIH    83886080ull
#define OFF_WHH    84410368ull
#define OFF_WXH    84934656ull
#define OFF_WICAT  85065728ull   // [Whm|Whl] interleaved 64-col blocks, N=256
#define OFF_W1CAT  85327872ull   // [Wg1|Wp1], N=1024
#define OFF_WG2    85590016ull
#define OFF_WP2    85721088ull
#define OFF_WMU    85852160ull
#define OFF_WLV    85884928ull
#define OFF_EW1    85917696ull
#define OFF_EW2    86048768ull
#define OFF_EW3    86573056ull
#define OFF_B1CAT  87097344ull   // fp32 [1024]
#define OFF_BICAT  87101440ull   // fp32 [256]
#define OFF_HC     87102464ull   // (64,512) bf16
#define OFF_XQ     87168000ull   // (64,128) bf16
#define OFF_U1     87184384ull   // (64,1024) bf16
#define OFF_PM     87315456ull   // (64,128) bf16
#define OFF_MU     87331840ull   // (64,128) bf16
#define OFF_XG     87348224ull   // (64,128) bf16
#define OFF_XPCNT  87364608ull   // int[1024]
#define OFF_RNNF   87368704ull   // int[16]
#define OFF_INFAF  87368768ull   // int[8]
#define OFF_INFBF  87368800ull   // int[8]
#define OFF_GENAF  87368832ull   // int[16]
#define OFF_GENBF  87368896ull   // int[32]

// ---------------- d_out offsets (floats) ----------------
#define QX_O  0ull
#define QMU_O 8388608ull
#define QLV_O 16777216ull
#define PX_O  25165824ull
#define PMU_O 33554432ull
#define PLV_O 41943040ull
#define Y_O   50331648ull

#define SMEM_SCAN 157696
#define SMEM_EMIS 133120

struct P {
  char* ws; float* out;
  const float *data, *eps_q, *eps_p;
  const float *Wih, *Whh, *bih, *bhh, *h0, *xq0, *x0;
  const float *Wxh, *bxh, *Whm, *bhm, *Whl, *bhl;
  const float *Wg1, *bg1, *Wg2, *bg2, *Wp1, *bp1, *Wp2, *bp2, *Wmu, *bmu, *Wlv, *blv;
  const float *eW1, *eb1, *eW2, *eb2, *eW3, *eb3;
};

__device__ __forceinline__ short f2bf(float f) {
  union { float f; uint32_t u; } v; v.f = f;
  uint32_t r = (v.u + 0x7FFFu + ((v.u >> 16) & 1u)) >> 16;
  return (short)(uint16_t)r;
}
__device__ __forceinline__ float bf2f(short s) {
  union { uint32_t u; float f; } v; v.u = ((uint32_t)(uint16_t)s) << 16;
  return v.f;
}
__device__ __forceinline__ bf16x8 ldfrag(const short* pp) { return *(const bf16x8*)pp; }
__device__ __forceinline__ bf16x8 cvt8p(const float* pp) {
  bf16x8 r;
#pragma unroll
  for (int i = 0; i < 8; ++i) r[i] = (__bf16)pp[i];
  return r;
}
__device__ __forceinline__ bf16x8 relu8(bf16x8 a) {
  s16x8 s = __builtin_bit_cast(s16x8, a);
#pragma unroll
  for (int i = 0; i < 8; ++i) s[i] = (s[i] < 0) ? (short)0 : s[i];
  return __builtin_bit_cast(bf16x8, s);
}
__device__ __forceinline__ int ldflag(int* pp) {
  return __hip_atomic_load(pp, __ATOMIC_RELAXED, __HIP_MEMORY_SCOPE_AGENT);
}
__device__ __forceinline__ void stflag(int* pp, int v) {
  __hip_atomic_store(pp, v, __ATOMIC_RELAXED, __HIP_MEMORY_SCOPE_AGENT);
}
// wave0 polls flags[0..n) >= target; then block-wide acquire.
__device__ __forceinline__ void waitf(int* f, int n, int target) {
  if (threadIdx.x < 64) {
    const int ln = threadIdx.x;
    while (1) {
      int v = (ln < n) ? ldflag(f + ln) : target;
      if (__all(v >= target)) break;
      __builtin_amdgcn_s_sleep(1);
    }
  }
  __syncthreads();
  __threadfence();
}
__device__ __forceinline__ void pubf(int* f, int val) {
  __threadfence();
  __syncthreads();
  if (threadIdx.x == 0) stflag(f, val);
}
__device__ __forceinline__ void cpy16(void* dst, const void* src, int n16) {
  float4* d = (float4*)dst; const float4* s = (const float4*)src;
  for (int i = threadIdx.x; i < n16; i += 256) d[i] = s[i];
}

// pack W (K x N, row-major fp32) into MFMA-B fragment order:
// dst[((nt*KT+kt)*64+lane)*8+j] = W[kt*32+(lane>>4)*8+j][nt*16+(lane&15)]
__device__ __forceinline__ void pack_w(short* dst, const float* src, int KT, int N, int idx) {
  int tile = idx >> 9, rem = idx & 511;
  int lane = rem >> 3, j = rem & 7;
  int nt = tile / KT, kt = tile - nt * KT;
  int k = kt * 32 + ((lane >> 4) << 3) + j, n = (nt << 4) + (lane & 15);
  dst[idx] = f2bf(src[(int64_t)k * N + n]);
}

__global__ void __launch_bounds__(256) k_prep(P p) {
  char* ws = p.ws;
  const int64_t total = 1608032;
  for (int64_t i = (int64_t)blockIdx.x * 256 + threadIdx.x; i < total;
       i += (int64_t)gridDim.x * 256) {
    int64_t r = i;
    if (r < 262144) { pack_w((short*)(ws + OFF_WIH), p.Wih, 16, 512, (int)r); continue; }
    r -= 262144;
    if (r < 262144) { pack_w((short*)(ws + OFF_WHH), p.Whh, 16, 512, (int)r); continue; }
    r -= 262144;
    if (r < 65536) { pack_w((short*)(ws + OFF_WXH), p.Wxh, 4, 512, (int)r); continue; }
    r -= 65536;
    if (r < 131072) {  // Wicat: [mu0-63|lv0-63|mu64-127|lv64-127], KT=16
      int idx = (int)r;
      int tile = idx >> 9, rem = idx & 511, lane = rem >> 3, jj = rem & 7;
      int nt = tile >> 4, kt = tile & 15;
      int k = kt * 32 + ((lane >> 4) << 3) + jj, ccol = (nt << 4) + (lane & 15);
      int pair = ccol >> 7, within = ccol & 127, sub = within >> 6;
      int col = (within & 63) + (pair << 6);
      const float* s = sub ? p.Whl : p.Whm;
      ((short*)(ws + OFF_WICAT))[idx] = f2bf(s[(int64_t)k * 128 + col]);
      continue;
    }
    r -= 131072;
    if (r < 131072) {  // W1cat = [Wg1|Wp1], KT=4, N=1024
      int idx = (int)r;
      int tile = idx >> 9, rem = idx & 511, lane = rem >> 3, jj = rem & 7;
      int nt = tile >> 2, kt = tile & 3;
      int k = kt * 32 + ((lane >> 4) << 3) + jj, ccol = (nt << 4) + (lane & 15);
      const float* s = (ccol < 512) ? p.Wg1 : p.Wp1;
      ((short*)(ws + OFF_W1CAT))[idx] = f2bf(s[(int64_t)k * 512 + (ccol & 511)]);
      continue;
    }
    r -= 131072;
    if (r < 65536) { pack_w((short*)(ws + OFF_WG2), p.Wg2, 16, 128, (int)r); continue; }
    r -= 65536;
    if (r < 65536) { pack_w((short*)(ws + OFF_WP2), p.Wp2, 16, 128, (int)r); continue; }
    r -= 65536;
    if (r < 16384) { pack_w((short*)(ws + OFF_WMU), p.Wmu, 4, 128, (int)r); continue; }
    r -= 16384;
    if (r < 16384) { pack_w((short*)(ws + OFF_WLV), p.Wlv, 4, 128, (int)r); continue; }
    r -= 16384;
    if (r < 65536) { pack_w((short*)(ws + OFF_EW1), p.eW1, 4, 512, (int)r); continue; }
    r -= 65536;
    if (r < 262144) { pack_w((short*)(ws + OFF_EW2), p.eW2, 16, 512, (int)r); continue; }
    r -= 262144;
    if (r < 262144) { pack_w((short*)(ws + OFF_EW3), p.eW3, 16, 512, (int)r); continue; }
    r -= 262144;
    if (r < 1024) { ((float*)(ws + OFF_B1CAT))[r] = (r < 512) ? p.bg1[r] : p.bp1[r - 512]; continue; }
    r -= 1024;
    if (r < 256) {
      int ccol = (int)r; int pair = ccol >> 7, within = ccol & 127, sub = within >> 6;
      int col = (within & 63) + (pair << 6);
      ((float*)(ws + OFF_BICAT))[ccol] = sub ? p.bhl[col] : p.bhm[col];
      continue;
    }
    r -= 256;
    ((int*)(ws + OFF_XPCNT))[r] = 0;  // r < 1120: all flags/counters
  }
}

// =====================================================================
// persistent scan kernel: 128 WGs.
//   [0,64):  xproj crew (x_proj GEMM, progress-counted)
//   [64,80): RNN crew (4 batch-groups x 4 col-slices) -> re-role as inf crew
//   [80,128): gen crew (4 groups x (4 A-WGs + 8 B-WGs)), 2 hops/step
// =====================================================================
__global__ void __launch_bounds__(256) k_scan(P p) {
  extern __shared__ char smem[];
  char* ws = p.ws;
  const int tid = threadIdx.x;
  const int lane = tid & 63, w = tid >> 6;
  const int l16 = lane & 15, quad = lane >> 4;
  const int wg = blockIdx.x;

  short* Xb   = (short*)(ws + OFF_X);
  short* qxbf = (short*)(ws + OFF_QXBF);
  int* xp_cnt = (int*)(ws + OFF_XPCNT);

  if (wg < 64) {
    // ---------------- xproj crew ----------------
    const int s = wg & 7, t0 = wg >> 3;
    const short* wih = (const short*)(ws + OFF_WIH);
    for (int tt = 0; tt < 128; ++tt) {
      const int t = t0 + (tt << 3);
      const int tsrc = 1023 - t;
      const float* arow = p.data + ((size_t)(w * 16 + l16) * 1024 + tsrc) * 512 + quad * 8;
      f32x4 acc[4] = {};
      for (int kt = 0; kt < 16; ++kt) {
        bf16x8 af = cvt8p(arow + kt * 32);
#pragma unroll
        for (int i = 0; i < 4; ++i) {
          const int nt = s * 4 + i;
          bf16x8 bw = ldfrag(wih + ((size_t)(nt * 16 + kt) * 64 + lane) * 8);
          acc[i] = MFMA16(af, bw, acc[i]);
        }
      }
      short* xrow = Xb + (size_t)t * 32768;
#pragma unroll
      for (int i = 0; i < 4; ++i) {
        const int col = (s * 4 + i) * 16 + l16;
        const float bias = p.bih[col] + p.bhh[col];
#pragma unroll
        for (int r = 0; r < 4; ++r) {
          const int row = w * 16 + quad * 4 + r;
          xrow[(size_t)row * 512 + col] = f2bf(acc[i][r] + bias);
        }
      }
      __threadfence();
      __syncthreads();
      if (tid == 0) atomicAdd(xp_cnt + t, 1);
    }
    return;
  }

  if (wg < 80) {
    // ---------------- RNN crew ----------------
    const int id = wg - 64, g = id >> 2, c = id & 3;
    short* lds = (short*)smem;
    cpy16(smem, ws + OFF_WHH + (size_t)c * 131072, 8192);  // 8 nt x 16 kt slice
    __syncthreads();
    int* rf = (int*)(ws + OFF_RNNF) + g * 4;
    for (int t = 0; t < 1024; ++t) {
      if (tid < 64) {
        while (1) {
          int ok = 1;
          if (tid < 4) { if (t > 0) ok = (ldflag(rf + tid) >= t); }
          else if (tid == 4) ok = (ldflag(xp_cnt + t) >= 8);
          if (__all(ok)) break;
          __builtin_amdgcn_s_sleep(1);
        }
      }
      __syncthreads();
      __threadfence();
      f32x4 acc[2] = {};
      const short* hrow = Xb + (size_t)(t > 0 ? t - 1 : 0) * 32768 + (size_t)(g * 16 + l16) * 512 + quad * 8;
      const float* h0p = p.h0 + quad * 8;
      for (int kt = 0; kt < 16; ++kt) {
        bf16x8 af = (t == 0) ? cvt8p(h0p + kt * 32) : ldfrag(hrow + kt * 32);
#pragma unroll
        for (int i = 0; i < 2; ++i) {
          const int ntl = w * 2 + i;
          bf16x8 bw = ldfrag(lds + ((size_t)(ntl * 16 + kt) * 64 + lane) * 8);
          acc[i] = MFMA16(af, bw, acc[i]);
        }
      }
      short* xrow = Xb + (size_t)t * 32768;
#pragma unroll
      for (int i = 0; i < 2; ++i) {
        const int col = c * 128 + (w * 2 + i) * 16 + l16;
#pragma unroll
        for (int r = 0; r < 4; ++r) {
          const int row = g * 16 + quad * 4 + r;
          const size_t o = (size_t)row * 512 + col;
          float h = acc[i][r] + bf2f(xrow[o]);
          xrow[o] = f2bf(h > 0.f ? h : 0.f);
        }
      }
      pubf(rf + c, t + 1);
    }
    // ---------------- re-role: inf crew ----------------
    waitf(rf, 4, 1024);  // whole group's hs complete
    const int g2 = g, r2 = c;
    short* hcb = (short*)(ws + OFF_HC);
    short* xqb = (short*)(ws + OFF_XQ);
    int* fa = (int*)(ws + OFF_INFAF) + g2 * 2;
    int* fb = (int*)(ws + OFF_INFBF) + g2 * 2;
    if (r2 < 2) {
      // stage A: h_c = 0.5*(tanh(x_prev@Wxh+bxh) + rnn_out[t]); 256-col slice
      cpy16(smem, ws + OFF_WXH + (size_t)r2 * 65536, 4096);
      short* lda = (short*)smem;
      __syncthreads();
      for (int t = 0; t < 1024; ++t) {
        if (t > 0) waitf(fb, 2, t);
        f32x4 acc[4] = {};
        const short* xrow = xqb + (size_t)(g2 * 16 + l16) * 128 + quad * 8;
        const float* xq0p = p.xq0 + quad * 8;
        for (int kt = 0; kt < 4; ++kt) {
          bf16x8 af = (t == 0) ? cvt8p(xq0p + kt * 32) : ldfrag(xrow + kt * 32);
#pragma unroll
          for (int i = 0; i < 4; ++i) {
            const int ntl = w * 4 + i;
            bf16x8 bw = ldfrag(lda + ((size_t)(ntl * 4 + kt) * 64 + lane) * 8);
            acc[i] = MFMA16(af, bw, acc[i]);
          }
        }
        const short* rsrc = Xb + (size_t)(1023 - t) * 32768;
#pragma unroll
        for (int i = 0; i < 4; ++i) {
          const int ng = r2 * 256 + (w * 4 + i) * 16 + l16;
          const float bx = p.bxh[ng];
#pragma unroll
          for (int r = 0; r < 4; ++r) {
            const int row = g2 * 16 + quad * 4 + r;
            const float u = acc[i][r] + bx;
            const float e = __expf(2.f * u);
            const float th = 1.f - 2.f / (e + 1.f);
            const float hc = 0.5f * (th + bf2f(rsrc[(size_t)row * 512 + ng]));
            hcb[(size_t)row * 512 + ng] = f2bf(hc);
          }
        }
        pubf(fa + r2, t + 1);
      }
    } else {
      // stage B: [mu|lv] slice from h_c; sample x_t; write q_* outputs
      const int j = r2 - 2;
      cpy16(smem, ws + OFF_WICAT + (size_t)j * 131072, 8192);
      short* ldb = (short*)smem;
      float* scr = (float*)(smem + 131072);  // [2][16][64]
      const float* bicat = (const float*)(ws + OFF_BICAT);
      __syncthreads();
      for (int t = 0; t < 1024; ++t) {
        waitf(fa, 2, t + 1);
        f32x4 acc[2] = {};
        const short* hrow2 = hcb + (size_t)(g2 * 16 + l16) * 512 + quad * 8;
        for (int kt = 0; kt < 16; ++kt) {
          bf16x8 af = ldfrag(hrow2 + kt * 32);
#pragma unroll
          for (int i = 0; i < 2; ++i) {
            const int ntl = w * 2 + i;
            bf16x8 bw = ldfrag(ldb + ((size_t)(ntl * 16 + kt) * 64 + lane) * 8);
            acc[i] = MFMA16(af, bw, acc[i]);
          }
        }
#pragma unroll
        for (int i = 0; i < 2; ++i) {
          const int catcol = (j * 8 + w * 2 + i) * 16 + l16;
          const int pair = catcol >> 7, within = catcol & 127, sub = within >> 6;
          const int col = (within & 63) + (pair << 6);
          const float bias = bicat[catcol];
          float* dbase = p.out + (sub ? QLV_O : QMU_O);
#pragma unroll
          for (int r = 0; r < 4; ++r) {
            const int row = quad * 4 + r, b = g2 * 16 + row;
            const float v = acc[i][r] + bias;
            dbase[(size_t)b * 131072 + (size_t)t * 128 + col] = v;
            scr[(sub * 16 + row) * 64 + (col & 63)] = v;
          }
        }
        __syncthreads();
        for (int i2 = tid; i2 < 1024; i2 += 256) {
          const int row = i2 >> 6, cl = i2 & 63;
          const int col = j * 64 + cl, b = g2 * 16 + row;
          const float m = scr[row * 64 + cl], l = scr[1024 + row * 64 + cl];
          const float xv = m + p.eps_q[((size_t)t * 64 + b) * 128 + col] * __expf(0.5f * l);
          p.out[QX_O + (size_t)b * 131072 + (size_t)t * 128 + col] = xv;
          qxbf[((size_t)b * 1024 + t) * 128 + col] = f2bf(xv);
          xqb[(size_t)b * 128 + col] = f2bf(xv);
        }
        pubf(fb + j, t + 1);
      }
    }
    return;
  }

  // ---------------- gen crew ----------------
  {
    const int id = wg - 80, g3 = id / 12, r3 = id % 12;
    short* u1b = (short*)(ws + OFF_U1);
    short* pmb = (short*)(ws + OFF_PM);
    short* mub = (short*)(ws + OFF_MU);
    short* xgb = (short*)(ws + OFF_XG);
    int* fga = (int*)(ws + OFF_GENAF) + g3 * 4;
    int* fgb = (int*)(ws + OFF_GENBF) + g3 * 8;
    if (r3 < 4) {
      // stage A: lv_{t-1}(full, redundant) -> x_{t-1} -> u1_t slice
      short* ldsW1 = (short*)smem;
      short* ldsLv = (short*)(smem + 65536);
      short* xl = (short*)(smem + 98304);  // [16][128] bf16, local x_{t-1}
      cpy16(smem, ws + OFF_W1CAT + (size_t)r3 * 65536, 4096);
      cpy16(smem + 65536, ws + OFF_WLV, 2048);
      const float* b1cat = (const float*)(ws + OFF_B1CAT);
      __syncthreads();
      for (int t = 0; t <= 1024; ++t) {
        if (t == 0) {
          for (int i2 = tid; i2 < 2048; i2 += 256) xl[i2] = f2bf(p.x0[i2 & 127]);
          __syncthreads();
        } else {
          waitf(fgb, 8, t);
          f32x4 acl[2] = {};
          const short* pmrow = pmb + (size_t)(g3 * 16 + l16) * 128 + quad * 8;
          for (int kt = 0; kt < 4; ++kt) {
            bf16x8 af = relu8(ldfrag(pmrow + kt * 32));
#pragma unroll
            for (int i = 0; i < 2; ++i) {
              const int ntl = w * 2 + i;
              bf16x8 bw = ldfrag(ldsLv + ((size_t)(ntl * 4 + kt) * 64 + lane) * 8);
              acl[i] = MFMA16(af, bw, acl[i]);
            }
          }
#pragma unroll
          for (int i = 0; i < 2; ++i) {
            const int col = (w * 2 + i) * 16 + l16;
            const float bl = p.blv[col];
#pragma unroll
            for (int r = 0; r < 4; ++r) {
              const int row = quad * 4 + r, b = g3 * 16 + row;
              const float lv = acl[i][r] + bl;
              const float mu = bf2f(mub[(size_t)(g3 * 16 + row) * 128 + col]);
              const float xv = mu + p.eps_p[((size_t)(t - 1) * 64 + b) * 128 + col] * __expf(0.5f * lv);
              if (w == r3) {
                p.out[PLV_O + (size_t)b * 131072 + (size_t)(t - 1) * 128 + col] = lv;
                p.out[PX_O + (size_t)b * 131072 + (size_t)(t - 1) * 128 + col] = xv;
              }
              xl[row * 128 + col] = f2bf(xv);
            }
          }
          __syncthreads();
        }
        if (t == 1024) break;
        f32x4 acc[4] = {};
        const short* xrow = xl + l16 * 128 + quad * 8;
        for (int kt = 0; kt < 4; ++kt) {
          bf16x8 af = ldfrag(xrow + kt * 32);
#pragma unroll
          for (int i = 0; i < 4; ++i) {
            const int ntl = w * 4 + i;
            bf16x8 bw = ldfrag(ldsW1 + ((size_t)(ntl * 4 + kt) * 64 + lane) * 8);
            acc[i] = MFMA16(af, bw, acc[i]);
          }
        }
#pragma unroll
        for (int i = 0; i < 4; ++i) {
          const int c1 = (r3 * 16 + w * 4 + i) * 16 + l16;
          const float bias = b1cat[c1];
#pragma unroll
          for (int r = 0; r < 4; ++r) {
            const int row = quad * 4 + r;
            const float u = acc[i][r] + bias;
            u1b[(size_t)(g3 * 16 + row) * 1024 + c1] = f2bf(u > 0.f ? u : 0.f);
          }
        }
        if (r3 == 0)
          for (int i2 = tid; i2 < 2048; i2 += 256) xgb[(size_t)g3 * 2048 + i2] = xl[i2];
        pubf(fga + r3, t + 1);
      }
    } else {
      // stage B: pm full (redundant), gate/xmu/mu 16-col slice
      const int j = r3 - 4;
      short* ldsP2 = (short*)smem;
      short* ldsG2 = (short*)(smem + 131072);
      short* ldsMu = (short*)(smem + 147456);
      short* spm = (short*)(smem + 151552);  // [16][128] bf16
      float* sg  = (float*)(smem + 155648);  // [16][16]
      float* sxm = (float*)(smem + 156672);  // [16][16]
      cpy16(smem, ws + OFF_WP2, 8192);
      cpy16(smem + 131072, ws + OFF_WG2 + (size_t)j * 16384, 1024);
      cpy16(smem + 147456, ws + OFF_WMU + (size_t)j * 4096, 256);
      __syncthreads();
      for (int t = 0; t < 1024; ++t) {
        waitf(fga, 4, t + 1);
        f32x4 acc[2] = {};
        const short* u1p = u1b + (size_t)(g3 * 16 + l16) * 1024 + 512 + quad * 8;
        for (int kt = 0; kt < 16; ++kt) {
          bf16x8 af = ldfrag(u1p + kt * 32);
#pragma unroll
          for (int i = 0; i < 2; ++i) {
            const int ntl = w * 2 + i;
            bf16x8 bw = ldfrag(ldsP2 + ((size_t)(ntl * 16 + kt) * 64 + lane) * 8);
            acc[i] = MFMA16(af, bw, acc[i]);
          }
        }
#pragma unroll
        for (int i = 0; i < 2; ++i) {
          const int col = (w * 2 + i) * 16 + l16;
          const float bias = p.bp2[col];
#pragma unroll
          for (int r = 0; r < 4; ++r) spm[(quad * 4 + r) * 128 + col] = f2bf(acc[i][r] + bias);
        }
        if (w == 0) {
          f32x4 ga = {};
          const short* u1g = u1b + (size_t)(g3 * 16 + l16) * 1024 + quad * 8;
          for (int kt = 0; kt < 16; ++kt) {
            bf16x8 af = ldfrag(u1g + kt * 32);
            bf16x8 bw = ldfrag(ldsG2 + ((size_t)kt * 64 + lane) * 8);
            ga = MFMA16(af, bw, ga);
          }
#pragma unroll
          for (int r = 0; r < 4; ++r) sg[(quad * 4 + r) * 16 + l16] = ga[r];
        } else if (w == 1) {
          f32x4 xm = {};
          const short* xg = xgb + (size_t)(g3 * 16 + l16) * 128 + quad * 8;
          for (int kt = 0; kt < 4; ++kt) {
            bf16x8 af = ldfrag(xg + kt * 32);
            bf16x8 bw = ldfrag(ldsMu + ((size_t)kt * 64 + lane) * 8);
            xm = MFMA16(af, bw, xm);
          }
#pragma unroll
          for (int r = 0; r < 4; ++r) sxm[(quad * 4 + r) * 16 + l16] = xm[r];
        }
        __syncthreads();
        {
          const int row = tid >> 4, cl = tid & 15;
          const int col = j * 16 + cl, b = g3 * 16 + row;
          const float gv = 1.f / (1.f + __expf(-(sg[row * 16 + cl] + p.bg2[col])));
          const float xmv = sxm[row * 16 + cl] + p.bmu[col];
          const float pmv = bf2f(spm[row * 128 + col]);
          const float mu = (1.f - gv) * xmv + gv * pmv;
          mub[(size_t)b * 128 + col] = f2bf(mu);
          p.out[PMU_O + (size_t)b * 131072 + (size_t)t * 128 + col] = mu;
        }
        if (j == 0)
          for (int i2 = tid; i2 < 2048; i2 += 256) pmb[(size_t)g3 * 2048 + i2] = spm[i2];
        pubf(fgb + j, t + 1);
      }
    }
    return;
  }
}

// =====================================================================
// fused emission MLP: y = sigmoid(relu(relu(qx@W1+b1)@W2+b2)@W3+b3)
// =====================================================================
__global__ void __launch_bounds__(256) k_emis(P p) {
  extern __shared__ char smem[];
  short* h1 = (short*)smem;            // [64][520] bf16 (pad 8 -> 2-way banks)
  short* h2 = (short*)(smem + 66560);  // [64][520]
  const int tid = threadIdx.x, lane = tid & 63, w = tid >> 6;
  const int l16 = lane & 15, quad = lane >> 4;
  const size_t m0 = (size_t)blockIdx.x * 64;
  const short* qx  = (const short*)(p.ws + OFF_QXBF);
  const short* ew1 = (const short*)(p.ws + OFF_EW1);
  const short* ew2 = (const short*)(p.ws + OFF_EW2);
  const short* ew3 = (const short*)(p.ws + OFF_EW3);
  for (int nc = 0; nc < 2; ++nc) {
    f32x4 acc[4][4] = {};
    for (int kt = 0; kt < 4; ++kt) {
      bf16x8 bw[4];
#pragma unroll
      for (int i = 0; i < 4; ++i) {
        const int nt = w * 8 + nc * 4 + i;
        bw[i] = ldfrag(ew1 + ((size_t)(nt * 4 + kt) * 64 + lane) * 8);
      }
#pragma unroll
      for (int mt = 0; mt < 4; ++mt) {
        bf16x8 af = ldfrag(qx + (m0 + mt * 16 + l16) * 128 + kt * 32 + quad * 8);
#pragma unroll
        for (int i = 0; i < 4; ++i) acc[mt][i] = MFMA16(af, bw[i], acc[mt][i]);
      }
    }
#pragma unroll
    for (int mt = 0; mt < 4; ++mt)
#pragma unroll
      for (int i = 0; i < 4; ++i) {
        const int col = (w * 8 + nc * 4 + i) * 16 + l16;
        const float bias = p.eb1[col];
#pragma unroll
        for (int r = 0; r < 4; ++r) {
          const float v = acc[mt][i][r] + bias;
          h1[(mt * 16 + quad * 4 + r) * 520 + col] = f2bf(v > 0.f ? v : 0.f);
        }
      }
  }
  __syncthreads();
  for (int nc = 0; nc < 2; ++nc) {
    f32x4 acc[4][4] = {};
    for (int kt = 0; kt < 16; ++kt) {
      bf16x8 bw[4];
#pragma unroll
      for (int i = 0; i < 4; ++i) {
        const int nt = w * 8 + nc * 4 + i;
        bw[i] = ldfrag(ew2 + ((size_t)(nt * 16 + kt) * 64 + lane) * 8);
      }
#pragma unroll
      for (int mt = 0; mt < 4; ++mt) {
        bf16x8 af = ldfrag(h1 + (mt * 16 + l16) * 520 + kt * 32 + quad * 8);
#pragma unroll
        for (int i = 0; i < 4; ++i) acc[mt][i] = MFMA16(af, bw[i], acc[mt][i]);
      }
    }
#pragma unroll
    for (int mt = 0; mt < 4; ++mt)
#pragma unroll
      for (int i = 0; i < 4; ++i) {
        const int col = (w * 8 + nc * 4 + i) * 16 + l16;
        const float bias = p.eb2[col];
#pragma unroll
        for (int r = 0; r < 4; ++r) {
          const float v = acc[mt][i][r] + bias;
          h2[(mt * 16 + quad * 4 + r) * 520 + col] = f2bf(v > 0.f ? v : 0.f);
        }
      }
  }
  __syncthreads();
  for (int nc = 0; nc < 2; ++nc) {
    f32x4 acc[4][4] = {};
    for (int kt = 0; kt < 16; ++kt) {
      bf16x8 bw[4];
#pragma unroll
      for (int i = 0; i < 4; ++i) {
        const int nt = w * 8 + nc * 4 + i;
        bw[i] = ldfrag(ew3 + ((size_t)(nt * 16 + kt) * 64 + lane) * 8);
      }
#pragma unroll
      for (int mt = 0; mt < 4; ++mt) {
        bf16x8 af = ldfrag(h2 + (mt * 16 + l16) * 520 + kt * 32 + quad * 8);
#pragma unroll
        for (int i = 0; i < 4; ++i) acc[mt][i] = MFMA16(af, bw[i], acc[mt][i]);
      }
    }
#pragma unroll
    for (int mt = 0; mt < 4; ++mt)
#pragma unroll
      for (int i = 0; i < 4; ++i) {
        const int col = (w * 8 + nc * 4 + i) * 16 + l16;
        const float bias = p.eb3[col];
#pragma unroll
        for (int r = 0; r < 4; ++r) {
          const size_t m = m0 + mt * 16 + quad * 4 + r;
          const size_t b = m >> 10, tt2 = m & 1023;
          const float v = acc[mt][i][r] + bias;
          p.out[Y_O + (b << 19) + tt2 * 512 + col] = 1.f / (1.f + __expf(-v));
        }
      }
  }
}

extern "C" void kernel_launch(void* const* d_in, const int* in_sizes, int n_in,
                              void* d_out, int out_size, void* d_ws, size_t ws_size,
                              hipStream_t stream) {
  (void)in_sizes; (void)n_in; (void)out_size; (void)ws_size;
  P p;
  p.ws = (char*)d_ws; p.out = (float*)d_out;
  p.data = (const float*)d_in[0];
  p.eps_q = (const float*)d_in[1];
  p.eps_p = (const float*)d_in[2];
  p.Wih = (const float*)d_in[3]; p.Whh = (const float*)d_in[4];
  p.bih = (const float*)d_in[5]; p.bhh = (const float*)d_in[6];
  p.h0 = (const float*)d_in[7]; p.xq0 = (const float*)d_in[8]; p.x0 = (const float*)d_in[9];
  p.Wxh = (const float*)d_in[10]; p.bxh = (const float*)d_in[11];
  p.Whm = (const float*)d_in[12]; p.bhm = (const float*)d_in[13];
  p.Whl = (const float*)d_in[14]; p.bhl = (const float*)d_in[15];
  p.Wg1 = (const float*)d_in[16]; p.bg1 = (const float*)d_in[17];
  p.Wg2 = (const float*)d_in[18]; p.bg2 = (const float*)d_in[19];
  p.Wp1 = (const float*)d_in[20]; p.bp1 = (const float*)d_in[21];
  p.Wp2 = (const float*)d_in[22]; p.bp2 = (const float*)d_in[23];
  p.Wmu = (const float*)d_in[24]; p.bmu = (const float*)d_in[25];
  p.Wlv = (const float*)d_in[26]; p.blv = (const float*)d_in[27];
  p.eW1 = (const float*)d_in[28]; p.eb1 = (const float*)d_in[29];
  p.eW2 = (const float*)d_in[30]; p.eb2 = (const float*)d_in[31];
  p.eW3 = (const float*)d_in[32]; p.eb3 = (const float*)d_in[33];

  hipFuncSetAttribute(reinterpret_cast<const void*>(k_scan),
                      hipFuncAttributeMaxDynamicSharedMemorySize, SMEM_SCAN);
  hipFuncSetAttribute(reinterpret_cast<const void*>(k_emis),
                      hipFuncAttributeMaxDynamicSharedMemorySize, SMEM_EMIS);

  k_prep<<<dim3(2048), dim3(256), 0, stream>>>(p);
  k_scan<<<dim3(128), dim3(256), SMEM_SCAN, stream>>>(p);
  k_emis<<<dim3(1024), dim3(256), SMEM_EMIS, stream>>>(p);
}